// Round 4
// baseline (687.607 us; speedup 1.0000x reference)
//
#include <hip/hip_runtime.h>
#include <hip/hip_bf16.h>
#include <stdint.h>

#define HDIM 1024
#define FDIM 1024
#define TTOK 2048
#define CAP  2048
#define MSZ  (1024*1024)

typedef __attribute__((ext_vector_type(8))) __bf16 bf16x8;
typedef __attribute__((ext_vector_type(4))) float  f32x4;

static __device__ __forceinline__ unsigned short f2bf(float v) {
  unsigned int u = __float_as_uint(v);
  u += 0x7FFF + ((u >> 16) & 1);   // RNE
  return (unsigned short)(u >> 16);
}

// ---------------- fused prep: transpose (blocks 0..6911) + x-cvt (..7935)
// ---------------- + router (..8447), all independent, one dispatch ----------
__global__ __launch_bounds__(256) void k_prep(
    const float* __restrict__ x, const float* __restrict__ wg,
    const float* __restrict__ wgp, const float* __restrict__ wsg,
    const float* __restrict__ wup, const float* __restrict__ wsu,
    const float* __restrict__ wdp, const float* __restrict__ wsd,
    unsigned short* __restrict__ wB, unsigned short* __restrict__ xb,
    int* __restrict__ counts, int* __restrict__ tok_id, float* __restrict__ tok_w) {
  int b = blockIdx.x;
  int tid = threadIdx.x;
  if (b < 6912) {
    // ---- weight transpose fp32 [R][C] -> bf16 [C][R], no LDS ----
    int m = b >> 8;                 // 0..26
    int rblk = (b >> 4) & 15, cblk = b & 15;
    const float* src;
    if (m < 8)       src = wgp + (size_t)m * MSZ;
    else if (m == 8) src = wsg;
    else if (m < 17) src = wup + (size_t)(m - 9) * MSZ;
    else if (m == 17) src = wsu;
    else if (m < 26) src = wdp + (size_t)(m - 18) * MSZ;
    else             src = wsd;
    unsigned short* dst = wB + (size_t)m * MSZ;
    int w = tid >> 6, L = tid & 63;
    int c  = cblk * 64 + L;         // src column = dst row
    int rb = rblk * 64;
    #pragma unroll
    for (int half = 0; half < 2; half++) {
      int r0 = rb + half * 32 + w * 8;
      uint4 v;
      unsigned pk[4];
      #pragma unroll
      for (int j = 0; j < 4; j++) {
        unsigned short lo = f2bf(src[(size_t)(r0 + 2 * j)     * 1024 + c]);
        unsigned short hi = f2bf(src[(size_t)(r0 + 2 * j + 1) * 1024 + c]);
        pk[j] = (unsigned)lo | ((unsigned)hi << 16);
      }
      v.x = pk[0]; v.y = pk[1]; v.z = pk[2]; v.w = pk[3];
      *(uint4*)(dst + (size_t)c * 1024 + r0) = v;
    }
  } else if (b < 6912 + 1024) {
    // ---- x fp32 -> bf16 (8 elems/thread) + shared-expert identity list ----
    int i = (b - 6912) * 256 + tid;
    const float4* in4 = (const float4*)x;
    float4 f0 = in4[i * 2], f1 = in4[i * 2 + 1];
    uint4 v;
    v.x = (unsigned)f2bf(f0.x) | ((unsigned)f2bf(f0.y) << 16);
    v.y = (unsigned)f2bf(f0.z) | ((unsigned)f2bf(f0.w) << 16);
    v.z = (unsigned)f2bf(f1.x) | ((unsigned)f2bf(f1.y) << 16);
    v.w = (unsigned)f2bf(f1.z) | ((unsigned)f2bf(f1.w) << 16);
    *((uint4*)(xb + (size_t)i * 8)) = v;
    if (i < TTOK) { tok_id[8 * CAP + i] = i; tok_w[8 * CAP + i] = 1.0f; }
  } else {
    // ---- router: wave per token, fp32, top2 + softmax + compaction ----
    int t = ((b - 7936) << 2) + (tid >> 6);
    int L = tid & 63;
    const float* xr = x + (size_t)t * HDIM;
    float acc[8] = {0, 0, 0, 0, 0, 0, 0, 0};
    for (int h = L; h < HDIM; h += 64) {
      float xv = xr[h];
      const float* wr = wg + h * 8;
      #pragma unroll
      for (int e = 0; e < 8; e++) acc[e] += xv * wr[e];
    }
    #pragma unroll
    for (int e = 0; e < 8; e++) {
      float v = acc[e];
      for (int off = 32; off > 0; off >>= 1) v += __shfl_xor(v, off);
      acc[e] = v;
    }
    if (L == 0) {
      int i1 = 0; float v1 = acc[0];
      #pragma unroll
      for (int e = 1; e < 8; e++) if (acc[e] > v1) { v1 = acc[e]; i1 = e; }
      int i2 = -1; float v2 = -1e30f;
      #pragma unroll
      for (int e = 0; e < 8; e++) if (e != i1 && acc[e] > v2) { v2 = acc[e]; i2 = e; }
      float ex = __expf(v2 - v1);
      float w1 = 1.f / (1.f + ex);
      float w2 = 1.f - w1;
      int p1 = atomicAdd(&counts[i1], 1);
      tok_id[i1 * CAP + p1] = t; tok_w[i1 * CAP + p1] = w1;
      int p2 = atomicAdd(&counts[i2], 1);
      tok_id[i2 * CAP + p2] = t; tok_w[i2 * CAP + p2] = w2;
    }
  }
}

// ---------------- GEMM1: act = silu(x@Wg) * (x@Wu) ---------------------------
// NO LDS, NO barriers: A and B fragments loaded straight into VGPRs with a
// 2-deep register ping-pong; compiler emits fine-grained vmcnt.  Block =
// 4 waves (2x2), block tile M128 x N64 (per output), wave 64x32 per output.
#define G1_REFILL(B, KO) \
  { _Pragma("unroll") for (int mt = 0; mt < 4; mt++) \
      aF[B][mt] = *(const bf16x8*)(ap[mt] + (KO)); \
    _Pragma("unroll") for (int nt = 0; nt < 2; nt++) { \
      bgF[B][nt] = *(const bf16x8*)(bg[nt] + (KO)); \
      buF[B][nt] = *(const bf16x8*)(bu[nt] + (KO)); } }
#define G1_COMPUTE(B) \
  { _Pragma("unroll") for (int mt = 0; mt < 4; mt++) \
    _Pragma("unroll") for (int nt = 0; nt < 2; nt++) { \
      accg[mt][nt] = __builtin_amdgcn_mfma_f32_16x16x32_bf16(aF[B][mt], bgF[B][nt], accg[mt][nt], 0, 0, 0); \
      accu[mt][nt] = __builtin_amdgcn_mfma_f32_16x16x32_bf16(aF[B][mt], buF[B][nt], accu[mt][nt], 0, 0, 0); } }

__global__ __launch_bounds__(256) void k_gemm1(
    const unsigned short* __restrict__ xb, const unsigned short* __restrict__ wB,
    const int* __restrict__ counts, const int* __restrict__ tok_id,
    unsigned short* __restrict__ actb) {
  int e = blockIdx.z;
  int Ne = (e == 8) ? TTOK : counts[e];
  int rb = blockIdx.x << 7;
  if (rb >= Ne) return;
  int nb = blockIdx.y << 6;
  const unsigned short* wgp = wB + (size_t)e * MSZ;        // [F][H] bf16
  const unsigned short* wup = wB + (size_t)(9 + e) * MSZ;  // [F][H] bf16
  int tid = threadIdx.x;
  int w = tid >> 6, L = tid & 63;
  int quad = L >> 4, l15 = L & 15;
  int wr = w >> 1, wc = w & 1;
  const int* tlist = tok_id + e * CAP + rb;
  const unsigned short* ap[4];
  #pragma unroll
  for (int mt = 0; mt < 4; mt++) {
    int row = (wr << 6) + (mt << 4) + l15;
    int t = (rb + row < Ne) ? tlist[row] : tlist[0];
    ap[mt] = xb + (size_t)t * 1024 + (quad << 3);
  }
  const unsigned short *bg[2], *bu[2];
  #pragma unroll
  for (int nt = 0; nt < 2; nt++) {
    int n = nb + (wc << 5) + (nt << 4) + l15;
    bg[nt] = wgp + (size_t)n * 1024 + (quad << 3);
    bu[nt] = wup + (size_t)n * 1024 + (quad << 3);
  }
  f32x4 accg[4][2], accu[4][2];
  #pragma unroll
  for (int mt = 0; mt < 4; mt++)
    #pragma unroll
    for (int nt = 0; nt < 2; nt++) {
      accg[mt][nt] = (f32x4){0.f, 0.f, 0.f, 0.f};
      accu[mt][nt] = (f32x4){0.f, 0.f, 0.f, 0.f};
    }
  bf16x8 aF[2][4], bgF[2][2], buF[2][2];
  G1_REFILL(0, 0)
  G1_REFILL(1, 32)
  for (int it = 0; it < 15; it++) {
    G1_COMPUTE(0)
    G1_REFILL(0, (it * 2 + 2) * 32)
    G1_COMPUTE(1)
    G1_REFILL(1, (it * 2 + 3) * 32)
  }
  G1_COMPUTE(0)
  G1_COMPUTE(1)
  #pragma unroll
  for (int mt = 0; mt < 4; mt++)
    #pragma unroll
    for (int nt = 0; nt < 2; nt++)
      #pragma unroll
      for (int g = 0; g < 4; g++) {
        int r = (wr << 6) + (mt << 4) + (quad << 2) + g;
        if (rb + r < Ne) {
          float gv = accg[mt][nt][g], uv = accu[mt][nt][g];
          float av = gv / (1.f + __expf(-gv)) * uv;
          int f = nb + (wc << 5) + (nt << 4) + l15;
          actb[(size_t)(e * CAP + rb + r) * 1024 + f] = f2bf(av);
        }
      }
}

// ---------------- GEMM2: out += w_t * (act @ Wd), atomic accumulate ----------
// Same no-LDS/no-barrier structure.  Block tile M128 x N128, wave 64x64.
#define G2_REFILL(B, KO) \
  { _Pragma("unroll") for (int mt = 0; mt < 4; mt++) \
      aF[B][mt] = *(const bf16x8*)(ap[mt] + (KO)); \
    _Pragma("unroll") for (int nt = 0; nt < 4; nt++) \
      bF[B][nt] = *(const bf16x8*)(bp[nt] + (KO)); }
#define G2_COMPUTE(B) \
  { _Pragma("unroll") for (int mt = 0; mt < 4; mt++) \
    _Pragma("unroll") for (int nt = 0; nt < 4; nt++) \
      acc[mt][nt] = __builtin_amdgcn_mfma_f32_16x16x32_bf16(aF[B][mt], bF[B][nt], acc[mt][nt], 0, 0, 0); }

__global__ __launch_bounds__(256) void k_gemm2(
    const unsigned short* __restrict__ actb, const unsigned short* __restrict__ wB,
    const int* __restrict__ counts, const int* __restrict__ tok_id,
    const float* __restrict__ tok_w, float* __restrict__ out) {
  int e = blockIdx.z;
  int Ne = (e == 8) ? TTOK : counts[e];
  int rb = blockIdx.x << 7;
  if (rb >= Ne) return;
  int nb = blockIdx.y << 7;
  const unsigned short* wd = wB + (size_t)(18 + e) * MSZ;  // [H][F] bf16
  int tid = threadIdx.x;
  int w = tid >> 6, L = tid & 63;
  int quad = L >> 4, l15 = L & 15;
  int wr = w >> 1, wc = w & 1;
  const unsigned short* ap[4];
  #pragma unroll
  for (int mt = 0; mt < 4; mt++) {
    int row = (wr << 6) + (mt << 4) + l15;            // rows >= Ne read junk, discarded
    ap[mt] = actb + (size_t)(e * CAP + rb + row) * 1024 + (quad << 3);
  }
  const unsigned short* bp[4];
  #pragma unroll
  for (int nt = 0; nt < 4; nt++) {
    int n = nb + (wc << 6) + (nt << 4) + l15;
    bp[nt] = wd + (size_t)n * 1024 + (quad << 3);
  }
  f32x4 acc[4][4];
  #pragma unroll
  for (int mt = 0; mt < 4; mt++)
    #pragma unroll
    for (int nt = 0; nt < 4; nt++) acc[mt][nt] = (f32x4){0.f, 0.f, 0.f, 0.f};
  bf16x8 aF[2][4], bF[2][4];
  G2_REFILL(0, 0)
  G2_REFILL(1, 32)
  for (int it = 0; it < 15; it++) {
    G2_COMPUTE(0)
    G2_REFILL(0, (it * 2 + 2) * 32)
    G2_COMPUTE(1)
    G2_REFILL(1, (it * 2 + 3) * 32)
  }
  G2_COMPUTE(0)
  G2_COMPUTE(1)
  #pragma unroll
  for (int mt = 0; mt < 4; mt++)
    #pragma unroll
    for (int nt = 0; nt < 4; nt++)
      #pragma unroll
      for (int g = 0; g < 4; g++) {
        int r = (wr << 6) + (mt << 4) + (quad << 2) + g;
        if (rb + r < Ne) {
          int t = tok_id[e * CAP + rb + r];
          float wt = tok_w[e * CAP + rb + r];
          int hc = nb + (wc << 6) + (nt << 4) + l15;
          atomicAdd(out + (size_t)t * 1024 + hc, acc[mt][nt][g] * wt);
        }
      }
}

extern "C" void kernel_launch(void* const* d_in, const int* in_sizes, int n_in,
                              void* d_out, int out_size, void* d_ws, size_t ws_size,
                              hipStream_t stream) {
  (void)in_sizes; (void)n_in; (void)ws_size;
  const float* x   = (const float*)d_in[0];
  const float* wg  = (const float*)d_in[1];
  const float* wgp = (const float*)d_in[2];
  const float* wup = (const float*)d_in[3];
  const float* wdp = (const float*)d_in[4];
  const float* wsg = (const float*)d_in[5];
  const float* wsu = (const float*)d_in[6];
  const float* wsd = (const float*)d_in[7];
  float* out = (float*)d_out;
  char* ws = (char*)d_ws;
  // ws layout (bytes): wB 27*MSZ*2 = 56623104 | xb 4194304 | actb 37748736
  //                    | tok_id 73728 | tok_w 73728 | counts 64   (~94.1 MiB)
  unsigned short* wB   = (unsigned short*)ws;
  unsigned short* xb   = (unsigned short*)(ws + 56623104);
  unsigned short* actb = (unsigned short*)(ws + 56623104 + 4194304);
  int*   tok_id = (int*)(ws + 56623104 + 4194304 + 37748736);
  float* tok_w  = (float*)(ws + 56623104 + 4194304 + 37748736 + 73728);
  int*   counts = (int*)(ws + 56623104 + 4194304 + 37748736 + 147456);

  hipMemsetAsync(counts, 0, 64, stream);
  hipMemsetAsync(out, 0, (size_t)out_size * 4, stream);
  k_prep<<<8448, 256, 0, stream>>>(x, wg, wgp, wsg, wup, wsu, wdp, wsd,
                                   wB, xb, counts, tok_id, tok_w);
  k_gemm1<<<dim3(16, 16, 9), 256, 0, stream>>>(xb, wB, counts, tok_id, actb);
  k_gemm2<<<dim3(16, 8, 9), 256, 0, stream>>>(actb, wB, counts, tok_id, tok_w, out);
}

// Round 6
// 324.428 us; speedup vs baseline: 2.1194x; 2.1194x over previous
//
#include <hip/hip_runtime.h>
#include <hip/hip_bf16.h>
#include <stdint.h>

#define HDIM 1024
#define FDIM 1024
#define TTOK 2048
#define CAP  2048
#define MSZ  (1024*1024)

typedef __attribute__((ext_vector_type(8))) __bf16 bf16x8;
typedef __attribute__((ext_vector_type(4))) float  f32x4;

static __device__ __forceinline__ unsigned short f2bf(float v) {
  unsigned int u = __float_as_uint(v);
  u += 0x7FFF + ((u >> 16) & 1);   // RNE
  return (unsigned short)(u >> 16);
}

static __device__ __forceinline__ void gload_lds16(const void* g, void* l) {
  __builtin_amdgcn_global_load_lds(
      (const __attribute__((address_space(1))) unsigned int*)g,
      (__attribute__((address_space(3))) unsigned int*)l, 16, 0, 0);
}

// ---------------- fused prep: transpose + x-cvt + router, one dispatch -------
__global__ __launch_bounds__(256) void k_prep(
    const float* __restrict__ x, const float* __restrict__ wg,
    const float* __restrict__ wgp, const float* __restrict__ wsg,
    const float* __restrict__ wup, const float* __restrict__ wsu,
    const float* __restrict__ wdp, const float* __restrict__ wsd,
    unsigned short* __restrict__ wB, unsigned short* __restrict__ xb,
    int* __restrict__ counts, int* __restrict__ tok_id, float* __restrict__ tok_w) {
  int b = blockIdx.x;
  int tid = threadIdx.x;
  if (b < 6912) {
    // ---- weight transpose fp32 [R][C] -> bf16 [C][R], no LDS ----
    int m = b >> 8;                 // 0..26
    int rblk = (b >> 4) & 15, cblk = b & 15;
    const float* src;
    if (m < 8)       src = wgp + (size_t)m * MSZ;
    else if (m == 8) src = wsg;
    else if (m < 17) src = wup + (size_t)(m - 9) * MSZ;
    else if (m == 17) src = wsu;
    else if (m < 26) src = wdp + (size_t)(m - 18) * MSZ;
    else             src = wsd;
    unsigned short* dst = wB + (size_t)m * MSZ;
    int w = tid >> 6, L = tid & 63;
    int c  = cblk * 64 + L;         // src column = dst row
    int rb = rblk * 64;
    #pragma unroll
    for (int half = 0; half < 2; half++) {
      int r0 = rb + half * 32 + w * 8;
      uint4 v;
      unsigned pk[4];
      #pragma unroll
      for (int j = 0; j < 4; j++) {
        unsigned short lo = f2bf(src[(size_t)(r0 + 2 * j)     * 1024 + c]);
        unsigned short hi = f2bf(src[(size_t)(r0 + 2 * j + 1) * 1024 + c]);
        pk[j] = (unsigned)lo | ((unsigned)hi << 16);
      }
      v.x = pk[0]; v.y = pk[1]; v.z = pk[2]; v.w = pk[3];
      *(uint4*)(dst + (size_t)c * 1024 + r0) = v;
    }
  } else if (b < 6912 + 1024) {
    // ---- x fp32 -> bf16 (8 elems/thread) + shared-expert identity list ----
    int i = (b - 6912) * 256 + tid;
    const float4* in4 = (const float4*)x;
    float4 f0 = in4[i * 2], f1 = in4[i * 2 + 1];
    uint4 v;
    v.x = (unsigned)f2bf(f0.x) | ((unsigned)f2bf(f0.y) << 16);
    v.y = (unsigned)f2bf(f0.z) | ((unsigned)f2bf(f0.w) << 16);
    v.z = (unsigned)f2bf(f1.x) | ((unsigned)f2bf(f1.y) << 16);
    v.w = (unsigned)f2bf(f1.z) | ((unsigned)f2bf(f1.w) << 16);
    *((uint4*)(xb + (size_t)i * 8)) = v;
    if (i < TTOK) { tok_id[8 * CAP + i] = i; tok_w[8 * CAP + i] = 1.0f; }
    if (i == 0) counts[8] = TTOK;
  } else {
    // ---- router: wave per token, fp32, top2 + softmax + compaction ----
    int t = ((b - 7936) << 2) + (tid >> 6);
    int L = tid & 63;
    const float* xr = x + (size_t)t * HDIM;
    float acc[8] = {0, 0, 0, 0, 0, 0, 0, 0};
    for (int h = L; h < HDIM; h += 64) {
      float xv = xr[h];
      const float* wr = wg + h * 8;
      #pragma unroll
      for (int e = 0; e < 8; e++) acc[e] += xv * wr[e];
    }
    #pragma unroll
    for (int e = 0; e < 8; e++) {
      float v = acc[e];
      for (int off = 32; off > 0; off >>= 1) v += __shfl_xor(v, off);
      acc[e] = v;
    }
    if (L == 0) {
      int i1 = 0; float v1 = acc[0];
      #pragma unroll
      for (int e = 1; e < 8; e++) if (acc[e] > v1) { v1 = acc[e]; i1 = e; }
      int i2 = -1; float v2 = -1e30f;
      #pragma unroll
      for (int e = 0; e < 8; e++) if (e != i1 && acc[e] > v2) { v2 = acc[e]; i2 = e; }
      float ex = __expf(v2 - v1);
      float w1 = 1.f / (1.f + ex);
      float w2 = 1.f - w1;
      int p1 = atomicAdd(&counts[i1], 1);
      tok_id[i1 * CAP + p1] = t; tok_w[i1 * CAP + p1] = w1;
      int p2 = atomicAdd(&counts[i2], 1);
      tok_id[i2 * CAP + p2] = t; tok_w[i2 * CAP + p2] = w2;
    }
  }
}

// LDS tile layout (both GEMMs): row-major [row][64 bf16]; 16B chunk c of row R
// holds logical chunk c ^ (R&7) (conflict-free, verified 0 in round 2).
// Grids are 1D, decoded so all blocks sharing a B-tile (same expert, same nb)
// have equal lin%8 -> land on the same XCD -> one L2 fill per weight line.

// ---------------- GEMM1: act = silu(x@Wg) * (x@Wu), gathered rows ------------
// tile 128(M) x 64(N per output), BK=64; 4 waves 2x2; g and u share A.
__global__ __launch_bounds__(256, 4) void k_gemm1(
    const unsigned short* __restrict__ xb, const unsigned short* __restrict__ wB,
    const int* __restrict__ counts, const int* __restrict__ tok_id,
    unsigned short* __restrict__ actb) {
  int lin = blockIdx.x;
  int e = lin >> 8;
  int r9 = lin & 255;
  int nbi = (r9 & 7) | ((r9 >> 7) << 3);   // 0..15, constant mod-8 class per nb
  int mi  = (r9 >> 3) & 15;                // 0..15
  int Ne = (e == 8) ? TTOK : counts[e];    // counts[8] also set in k_prep
  int rb = mi << 7;
  if (rb >= Ne) return;
  int nb = nbi << 6;
  const unsigned short* wg = wB + (size_t)e * MSZ;        // [F][H] bf16
  const unsigned short* wu = wB + (size_t)(9 + e) * MSZ;  // [F][H] bf16
  __shared__ __align__(16) unsigned short As[128 * 64];
  __shared__ __align__(16) unsigned short Bgs[64 * 64];
  __shared__ __align__(16) unsigned short Bus[64 * 64];
  int tid = threadIdx.x;
  int w = tid >> 6, L = tid & 63;
  int quad = L >> 4, lane15 = L & 15;
  int wr = w >> 1, wc = w & 1;
  int l7 = lane15 & 7;
  int sw8 = ((L & 7) ^ (L >> 3)) << 3;    // swizzled global chunk offset (elems)
  const int* tlist = tok_id + e * CAP + rb;
  int trow[4];
  #pragma unroll
  for (int r = 0; r < 4; r++) {
    int row = (w << 5) + (r << 3) + (L >> 3);
    trow[r] = (rb + row < Ne) ? tlist[row] : 0;
  }
  f32x4 accg[4][2], accu[4][2];
  #pragma unroll
  for (int mt = 0; mt < 4; mt++)
    #pragma unroll
    for (int nt = 0; nt < 2; nt++) {
      accg[mt][nt] = (f32x4){0.f, 0.f, 0.f, 0.f};
      accu[mt][nt] = (f32x4){0.f, 0.f, 0.f, 0.f};
    }
  for (int it = 0; it < 16; it++) {
    int k0 = it << 6;
    #pragma unroll
    for (int r = 0; r < 4; r++)
      gload_lds16(xb + (size_t)trow[r] * 1024 + k0 + sw8, As + ((w << 2) + r) * 512);
    #pragma unroll
    for (int r = 0; r < 2; r++) {
      int fr = (((w << 1) + r) << 3) + (L >> 3);
      size_t go = (size_t)(nb + fr) * 1024 + k0 + sw8;
      gload_lds16(wg + go, Bgs + ((w << 1) + r) * 512);
      gload_lds16(wu + go, Bus + ((w << 1) + r) * 512);
    }
    __syncthreads();
    #pragma unroll
    for (int s = 0; s < 2; s++) {
      bf16x8 a[4], bg[2], bu[2];
      int ch = (s << 2) + quad;           // logical 16B chunk 0..7
      int po = ((ch ^ l7) << 3);          // physical element offset in row
      #pragma unroll
      for (int mt = 0; mt < 4; mt++)
        a[mt] = *(const bf16x8*)(As + (((wr << 6) + (mt << 4) + lane15) << 6) + po);
      #pragma unroll
      for (int nt = 0; nt < 2; nt++) {
        int rrow = ((wc << 5) + (nt << 4) + lane15) << 6;
        bg[nt] = *(const bf16x8*)(Bgs + rrow + po);
        bu[nt] = *(const bf16x8*)(Bus + rrow + po);
      }
      #pragma unroll
      for (int mt = 0; mt < 4; mt++)
        #pragma unroll
        for (int nt = 0; nt < 2; nt++) {
          accg[mt][nt] = __builtin_amdgcn_mfma_f32_16x16x32_bf16(a[mt], bg[nt], accg[mt][nt], 0, 0, 0);
          accu[mt][nt] = __builtin_amdgcn_mfma_f32_16x16x32_bf16(a[mt], bu[nt], accu[mt][nt], 0, 0, 0);
        }
    }
    __syncthreads();
  }
  #pragma unroll
  for (int mt = 0; mt < 4; mt++)
    #pragma unroll
    for (int nt = 0; nt < 2; nt++)
      #pragma unroll
      for (int g = 0; g < 4; g++) {
        int r = (wr << 6) + (mt << 4) + (quad << 2) + g;
        if (rb + r < Ne) {
          float gv = accg[mt][nt][g], uv = accu[mt][nt][g];
          float av = gv / (1.f + __expf(-gv)) * uv;
          int f = nb + (wc << 5) + (nt << 4) + lane15;
          actb[(size_t)(e * CAP + rb + r) * 1024 + f] = f2bf(av);
        }
      }
}

// ---------------- GEMM2: out += w_t * (act @ Wd), atomic accumulate ----------
// tile 128x128, BK=64; 4 waves 2x2 each 64x64.
__global__ __launch_bounds__(256, 4) void k_gemm2(
    const unsigned short* __restrict__ actb, const unsigned short* __restrict__ wB,
    const int* __restrict__ counts, const int* __restrict__ tok_id,
    const float* __restrict__ tok_w, float* __restrict__ out) {
  int lin = blockIdx.x;
  int e = lin >> 7;
  int r8 = lin & 127;
  int nbi = r8 & 7;                        // same nb -> same lin%8 -> same XCD
  int mi  = r8 >> 3;
  int Ne = (e == 8) ? TTOK : counts[e];    // counts[8] also set in k_prep
  int rb = mi << 7;
  if (rb >= Ne) return;
  int nb = nbi << 7;
  const unsigned short* wd = wB + (size_t)(18 + e) * MSZ;  // [H][F] bf16
  __shared__ __align__(16) unsigned short As[128 * 64];
  __shared__ __align__(16) unsigned short Bs[128 * 64];
  int tid = threadIdx.x;
  int w = tid >> 6, L = tid & 63;
  int quad = L >> 4, lane15 = L & 15;
  int wr = w >> 1, wc = w & 1;
  int l7 = lane15 & 7;
  int sw8 = ((L & 7) ^ (L >> 3)) << 3;
  const unsigned short* arow = actb + (size_t)(e * CAP + rb) * 1024;
  f32x4 acc[4][4];
  #pragma unroll
  for (int mt = 0; mt < 4; mt++)
    #pragma unroll
    for (int nt = 0; nt < 4; nt++) acc[mt][nt] = (f32x4){0.f, 0.f, 0.f, 0.f};
  for (int it = 0; it < 16; it++) {
    int k0 = it << 6;
    #pragma unroll
    for (int r = 0; r < 4; r++) {
      int row = (w << 5) + (r << 3) + (L >> 3);
      gload_lds16(arow + (size_t)row * 1024 + k0 + sw8, As + ((w << 2) + r) * 512);
      gload_lds16(wd + (size_t)(nb + row) * 1024 + k0 + sw8, Bs + ((w << 2) + r) * 512);
    }
    __syncthreads();
    #pragma unroll
    for (int s = 0; s < 2; s++) {
      bf16x8 a[4], b[4];
      int ch = (s << 2) + quad;
      int po = ((ch ^ l7) << 3);
      #pragma unroll
      for (int mt = 0; mt < 4; mt++)
        a[mt] = *(const bf16x8*)(As + (((wr << 6) + (mt << 4) + lane15) << 6) + po);
      #pragma unroll
      for (int nt = 0; nt < 4; nt++)
        b[nt] = *(const bf16x8*)(Bs + (((wc << 6) + (nt << 4) + lane15) << 6) + po);
      #pragma unroll
      for (int mt = 0; mt < 4; mt++)
        #pragma unroll
        for (int nt = 0; nt < 4; nt++)
          acc[mt][nt] = __builtin_amdgcn_mfma_f32_16x16x32_bf16(a[mt], b[nt], acc[mt][nt], 0, 0, 0);
    }
    __syncthreads();
  }
  #pragma unroll
  for (int mt = 0; mt < 4; mt++)
    #pragma unroll
    for (int nt = 0; nt < 4; nt++)
      #pragma unroll
      for (int g = 0; g < 4; g++) {
        int r = (wr << 6) + (mt << 4) + (quad << 2) + g;
        if (rb + r < Ne) {
          int t = tok_id[e * CAP + rb + r];
          float wt = tok_w[e * CAP + rb + r];
          int hc = nb + (wc << 6) + (nt << 4) + lane15;
          atomicAdd(out + (size_t)t * 1024 + hc, acc[mt][nt][g] * wt);
        }
      }
}

extern "C" void kernel_launch(void* const* d_in, const int* in_sizes, int n_in,
                              void* d_out, int out_size, void* d_ws, size_t ws_size,
                              hipStream_t stream) {
  (void)in_sizes; (void)n_in; (void)ws_size;
  const float* x   = (const float*)d_in[0];
  const float* wg  = (const float*)d_in[1];
  const float* wgp = (const float*)d_in[2];
  const float* wup = (const float*)d_in[3];
  const float* wdp = (const float*)d_in[4];
  const float* wsg = (const float*)d_in[5];
  const float* wsu = (const float*)d_in[6];
  const float* wsd = (const float*)d_in[7];
  float* out = (float*)d_out;
  char* ws = (char*)d_ws;
  // ws layout (bytes): wB 27*MSZ*2 = 56623104 | xb 4194304 | actb 37748736
  //                    | tok_id 73728 | tok_w 73728 | counts 64   (~94.1 MiB)
  unsigned short* wB   = (unsigned short*)ws;
  unsigned short* xb   = (unsigned short*)(ws + 56623104);
  unsigned short* actb = (unsigned short*)(ws + 56623104 + 4194304);
  int*   tok_id = (int*)(ws + 56623104 + 4194304 + 37748736);
  float* tok_w  = (float*)(ws + 56623104 + 4194304 + 37748736 + 73728);
  int*   counts = (int*)(ws + 56623104 + 4194304 + 37748736 + 147456);

  hipMemsetAsync(counts, 0, 64, stream);
  hipMemsetAsync(out, 0, (size_t)out_size * 4, stream);
  k_prep<<<8448, 256, 0, stream>>>(x, wg, wgp, wsg, wup, wsu, wdp, wsd,
                                   wB, xb, counts, tok_id, tok_w);
  k_gemm1<<<2304, 256, 0, stream>>>(xb, wB, counts, tok_id, actb);
  k_gemm2<<<1152, 256, 0, stream>>>(actb, wB, counts, tok_id, tok_w, out);
}

// Round 7
// 304.798 us; speedup vs baseline: 2.2559x; 1.0644x over previous
//
#include <hip/hip_runtime.h>
#include <hip/hip_bf16.h>
#include <stdint.h>

#define HDIM 1024
#define FDIM 1024
#define TTOK 2048
#define CAP  2048
#define MSZ  (1024*1024)

typedef __attribute__((ext_vector_type(8))) __bf16 bf16x8;
typedef __attribute__((ext_vector_type(4))) float  f32x4;

static __device__ __forceinline__ unsigned short f2bf(float v) {
  unsigned int u = __float_as_uint(v);
  u += 0x7FFF + ((u >> 16) & 1);   // RNE
  return (unsigned short)(u >> 16);
}

static __device__ __forceinline__ unsigned pk2(float a, float b) {
  return (unsigned)f2bf(a) | ((unsigned)f2bf(b) << 16);
}

static __device__ __forceinline__ void gload_lds16(const void* g, void* l) {
  __builtin_amdgcn_global_load_lds(
      (const __attribute__((address_space(1))) unsigned int*)g,
      (__attribute__((address_space(3))) unsigned int*)l, 16, 0, 0);
}

// ---------------- fused prep: transpose + x-cvt + router, one dispatch -------
// Transpose: register-blocked 8x4, no LDS, both sides >=128B-segment coalesced.
// blocks 0..3455: transpose (27 mats x 16 rblk x 8 cblk, tile 64r x 128c)
// blocks 3456..4479: x fp32->bf16 ; blocks 4480..4991: router
__global__ __launch_bounds__(256) void k_prep(
    const float* __restrict__ x, const float* __restrict__ wg,
    const float* __restrict__ wgp, const float* __restrict__ wsg,
    const float* __restrict__ wup, const float* __restrict__ wsu,
    const float* __restrict__ wdp, const float* __restrict__ wsd,
    unsigned short* __restrict__ wB, unsigned short* __restrict__ xb,
    int* __restrict__ counts, int* __restrict__ tok_id, float* __restrict__ tok_w) {
  int b = blockIdx.x;
  int tid = threadIdx.x;
  if (b < 3456) {
    int m = b >> 7;                  // 0..26
    int idx = b & 127;
    int rblk = idx >> 3, cblk = idx & 7;
    const float* src;
    if (m < 8)       src = wgp + (size_t)m * MSZ;
    else if (m == 8) src = wsg;
    else if (m < 17) src = wup + (size_t)(m - 9) * MSZ;
    else if (m == 17) src = wsu;
    else if (m < 26) src = wdp + (size_t)(m - 18) * MSZ;
    else             src = wsd;
    unsigned short* dst = wB + (size_t)m * MSZ;
    int rb = rblk << 6;              // src row base (64 rows)
    int cb = cblk << 7;              // src col base (128 cols)
    int r0 = (tid & 7) << 3;         // 8 src rows per thread
    int c0 = (tid >> 3) << 2;        // 4 src cols per thread
    float4 v[8];
    #pragma unroll
    for (int i = 0; i < 8; i++)
      v[i] = *(const float4*)(src + (size_t)(rb + r0 + i) * 1024 + cb + c0);
    #pragma unroll
    for (int j = 0; j < 4; j++) {
      float e0 = (j == 0) ? v[0].x : (j == 1) ? v[0].y : (j == 2) ? v[0].z : v[0].w;
      float e1 = (j == 0) ? v[1].x : (j == 1) ? v[1].y : (j == 2) ? v[1].z : v[1].w;
      float e2 = (j == 0) ? v[2].x : (j == 1) ? v[2].y : (j == 2) ? v[2].z : v[2].w;
      float e3 = (j == 0) ? v[3].x : (j == 1) ? v[3].y : (j == 2) ? v[3].z : v[3].w;
      float e4 = (j == 0) ? v[4].x : (j == 1) ? v[4].y : (j == 2) ? v[4].z : v[4].w;
      float e5 = (j == 0) ? v[5].x : (j == 1) ? v[5].y : (j == 2) ? v[5].z : v[5].w;
      float e6 = (j == 0) ? v[6].x : (j == 1) ? v[6].y : (j == 2) ? v[6].z : v[6].w;
      float e7 = (j == 0) ? v[7].x : (j == 1) ? v[7].y : (j == 2) ? v[7].z : v[7].w;
      uint4 o;
      o.x = pk2(e0, e1); o.y = pk2(e2, e3); o.z = pk2(e4, e5); o.w = pk2(e6, e7);
      *(uint4*)(dst + (size_t)(cb + c0 + j) * 1024 + rb + r0) = o;
    }
  } else if (b < 3456 + 1024) {
    // ---- x fp32 -> bf16 (8 elems/thread) + shared-expert identity list ----
    int i = (b - 3456) * 256 + tid;
    const float4* in4 = (const float4*)x;
    float4 f0 = in4[i * 2], f1 = in4[i * 2 + 1];
    uint4 v;
    v.x = pk2(f0.x, f0.y); v.y = pk2(f0.z, f0.w);
    v.z = pk2(f1.x, f1.y); v.w = pk2(f1.z, f1.w);
    *((uint4*)(xb + (size_t)i * 8)) = v;
    if (i < TTOK) { tok_id[8 * CAP + i] = i; tok_w[8 * CAP + i] = 1.0f; }
    if (i == 0) counts[8] = TTOK;
  } else {
    // ---- router: wave per token, fp32, top2 + softmax + compaction ----
    int t = ((b - 4480) << 2) + (tid >> 6);
    int L = tid & 63;
    const float* xr = x + (size_t)t * HDIM;
    float acc[8] = {0, 0, 0, 0, 0, 0, 0, 0};
    for (int h = L; h < HDIM; h += 64) {
      float xv = xr[h];
      const float* wr = wg + h * 8;
      #pragma unroll
      for (int e = 0; e < 8; e++) acc[e] += xv * wr[e];
    }
    #pragma unroll
    for (int e = 0; e < 8; e++) {
      float v = acc[e];
      for (int off = 32; off > 0; off >>= 1) v += __shfl_xor(v, off);
      acc[e] = v;
    }
    if (L == 0) {
      int i1 = 0; float v1 = acc[0];
      #pragma unroll
      for (int e = 1; e < 8; e++) if (acc[e] > v1) { v1 = acc[e]; i1 = e; }
      int i2 = -1; float v2 = -1e30f;
      #pragma unroll
      for (int e = 0; e < 8; e++) if (e != i1 && acc[e] > v2) { v2 = acc[e]; i2 = e; }
      float ex = __expf(v2 - v1);
      float w1 = 1.f / (1.f + ex);
      float w2 = 1.f - w1;
      int p1 = atomicAdd(&counts[i1], 1);
      tok_id[i1 * CAP + p1] = t; tok_w[i1 * CAP + p1] = w1;
      int p2 = atomicAdd(&counts[i2], 1);
      tok_id[i2 * CAP + p2] = t; tok_w[i2 * CAP + p2] = w2;
    }
  }
}

// LDS tile layout (both GEMMs): row-major [row][64 bf16]; 16B chunk c of row R
// holds logical chunk c ^ (R&7) (conflict-free, verified 0 in round 2).
// Grids are 1D, decoded so all blocks sharing a B-tile (same expert, same nb)
// have equal lin%8 -> land on the same XCD -> one L2 fill per weight line.

// ---------------- GEMM1: act = silu(x@Wg) * (x@Wu), gathered rows ------------
// tile 128(M) x 64(N per output), BK=64; 4 waves 2x2; g and u share A.
__global__ __launch_bounds__(256, 4) void k_gemm1(
    const unsigned short* __restrict__ xb, const unsigned short* __restrict__ wB,
    const int* __restrict__ counts, const int* __restrict__ tok_id,
    unsigned short* __restrict__ actb) {
  int lin = blockIdx.x;
  int e = lin >> 8;
  int r9 = lin & 255;
  int nbi = (r9 & 7) | ((r9 >> 7) << 3);   // 0..15, constant mod-8 class per nb
  int mi  = (r9 >> 3) & 15;                // 0..15
  int Ne = (e == 8) ? TTOK : counts[e];    // counts[8] also set in k_prep
  int rb = mi << 7;
  if (rb >= Ne) return;
  int nb = nbi << 6;
  const unsigned short* wg = wB + (size_t)e * MSZ;        // [F][H] bf16
  const unsigned short* wu = wB + (size_t)(9 + e) * MSZ;  // [F][H] bf16
  __shared__ __align__(16) unsigned short As[128 * 64];
  __shared__ __align__(16) unsigned short Bgs[64 * 64];
  __shared__ __align__(16) unsigned short Bus[64 * 64];
  int tid = threadIdx.x;
  int w = tid >> 6, L = tid & 63;
  int quad = L >> 4, lane15 = L & 15;
  int wr = w >> 1, wc = w & 1;
  int l7 = lane15 & 7;
  int sw8 = ((L & 7) ^ (L >> 3)) << 3;    // swizzled global chunk offset (elems)
  const int* tlist = tok_id + e * CAP + rb;
  int trow[4];
  #pragma unroll
  for (int r = 0; r < 4; r++) {
    int row = (w << 5) + (r << 3) + (L >> 3);
    trow[r] = (rb + row < Ne) ? tlist[row] : 0;
  }
  f32x4 accg[4][2], accu[4][2];
  #pragma unroll
  for (int mt = 0; mt < 4; mt++)
    #pragma unroll
    for (int nt = 0; nt < 2; nt++) {
      accg[mt][nt] = (f32x4){0.f, 0.f, 0.f, 0.f};
      accu[mt][nt] = (f32x4){0.f, 0.f, 0.f, 0.f};
    }
  for (int it = 0; it < 16; it++) {
    int k0 = it << 6;
    #pragma unroll
    for (int r = 0; r < 4; r++)
      gload_lds16(xb + (size_t)trow[r] * 1024 + k0 + sw8, As + ((w << 2) + r) * 512);
    #pragma unroll
    for (int r = 0; r < 2; r++) {
      int fr = (((w << 1) + r) << 3) + (L >> 3);
      size_t go = (size_t)(nb + fr) * 1024 + k0 + sw8;
      gload_lds16(wg + go, Bgs + ((w << 1) + r) * 512);
      gload_lds16(wu + go, Bus + ((w << 1) + r) * 512);
    }
    __syncthreads();
    #pragma unroll
    for (int s = 0; s < 2; s++) {
      bf16x8 a[4], bg[2], bu[2];
      int ch = (s << 2) + quad;           // logical 16B chunk 0..7
      int po = ((ch ^ l7) << 3);          // physical element offset in row
      #pragma unroll
      for (int mt = 0; mt < 4; mt++)
        a[mt] = *(const bf16x8*)(As + (((wr << 6) + (mt << 4) + lane15) << 6) + po);
      #pragma unroll
      for (int nt = 0; nt < 2; nt++) {
        int rrow = ((wc << 5) + (nt << 4) + lane15) << 6;
        bg[nt] = *(const bf16x8*)(Bgs + rrow + po);
        bu[nt] = *(const bf16x8*)(Bus + rrow + po);
      }
      #pragma unroll
      for (int mt = 0; mt < 4; mt++)
        #pragma unroll
        for (int nt = 0; nt < 2; nt++) {
          accg[mt][nt] = __builtin_amdgcn_mfma_f32_16x16x32_bf16(a[mt], bg[nt], accg[mt][nt], 0, 0, 0);
          accu[mt][nt] = __builtin_amdgcn_mfma_f32_16x16x32_bf16(a[mt], bu[nt], accu[mt][nt], 0, 0, 0);
        }
    }
    __syncthreads();
  }
  #pragma unroll
  for (int mt = 0; mt < 4; mt++)
    #pragma unroll
    for (int nt = 0; nt < 2; nt++)
      #pragma unroll
      for (int g = 0; g < 4; g++) {
        int r = (wr << 6) + (mt << 4) + (quad << 2) + g;
        if (rb + r < Ne) {
          float gv = accg[mt][nt][g], uv = accu[mt][nt][g];
          float av = gv / (1.f + __expf(-gv)) * uv;
          int f = nb + (wc << 5) + (nt << 4) + lane15;
          actb[(size_t)(e * CAP + rb + r) * 1024 + f] = f2bf(av);
        }
      }
}

// ---------------- GEMM2: out += w_t * (act @ Wd), atomic accumulate ----------
// tile 128x128, BK=64; 4 waves 2x2 each 64x64.
__global__ __launch_bounds__(256, 4) void k_gemm2(
    const unsigned short* __restrict__ actb, const unsigned short* __restrict__ wB,
    const int* __restrict__ counts, const int* __restrict__ tok_id,
    const float* __restrict__ tok_w, float* __restrict__ out) {
  int lin = blockIdx.x;
  int e = lin >> 7;
  int r8 = lin & 127;
  int nbi = r8 & 7;                        // same nb -> same lin%8 -> same XCD
  int mi  = r8 >> 3;
  int Ne = (e == 8) ? TTOK : counts[e];    // counts[8] also set in k_prep
  int rb = mi << 7;
  if (rb >= Ne) return;
  int nb = nbi << 7;
  const unsigned short* wd = wB + (size_t)(18 + e) * MSZ;  // [H][F] bf16
  __shared__ __align__(16) unsigned short As[128 * 64];
  __shared__ __align__(16) unsigned short Bs[128 * 64];
  int tid = threadIdx.x;
  int w = tid >> 6, L = tid & 63;
  int quad = L >> 4, lane15 = L & 15;
  int wr = w >> 1, wc = w & 1;
  int l7 = lane15 & 7;
  int sw8 = ((L & 7) ^ (L >> 3)) << 3;
  const unsigned short* arow = actb + (size_t)(e * CAP + rb) * 1024;
  f32x4 acc[4][4];
  #pragma unroll
  for (int mt = 0; mt < 4; mt++)
    #pragma unroll
    for (int nt = 0; nt < 4; nt++) acc[mt][nt] = (f32x4){0.f, 0.f, 0.f, 0.f};
  for (int it = 0; it < 16; it++) {
    int k0 = it << 6;
    #pragma unroll
    for (int r = 0; r < 4; r++) {
      int row = (w << 5) + (r << 3) + (L >> 3);
      gload_lds16(arow + (size_t)row * 1024 + k0 + sw8, As + ((w << 2) + r) * 512);
      gload_lds16(wd + (size_t)(nb + row) * 1024 + k0 + sw8, Bs + ((w << 2) + r) * 512);
    }
    __syncthreads();
    #pragma unroll
    for (int s = 0; s < 2; s++) {
      bf16x8 a[4], b[4];
      int ch = (s << 2) + quad;
      int po = ((ch ^ l7) << 3);
      #pragma unroll
      for (int mt = 0; mt < 4; mt++)
        a[mt] = *(const bf16x8*)(As + (((wr << 6) + (mt << 4) + lane15) << 6) + po);
      #pragma unroll
      for (int nt = 0; nt < 4; nt++)
        b[nt] = *(const bf16x8*)(Bs + (((wc << 6) + (nt << 4) + lane15) << 6) + po);
      #pragma unroll
      for (int mt = 0; mt < 4; mt++)
        #pragma unroll
        for (int nt = 0; nt < 4; nt++)
          acc[mt][nt] = __builtin_amdgcn_mfma_f32_16x16x32_bf16(a[mt], b[nt], acc[mt][nt], 0, 0, 0);
    }
    __syncthreads();
  }
  #pragma unroll
  for (int mt = 0; mt < 4; mt++)
    #pragma unroll
    for (int nt = 0; nt < 4; nt++)
      #pragma unroll
      for (int g = 0; g < 4; g++) {
        int r = (wr << 6) + (mt << 4) + (quad << 2) + g;
        if (rb + r < Ne) {
          int t = tok_id[e * CAP + rb + r];
          float wt = tok_w[e * CAP + rb + r];
          int hc = nb + (wc << 6) + (nt << 4) + lane15;
          atomicAdd(out + (size_t)t * 1024 + hc, acc[mt][nt][g] * wt);
        }
      }
}

extern "C" void kernel_launch(void* const* d_in, const int* in_sizes, int n_in,
                              void* d_out, int out_size, void* d_ws, size_t ws_size,
                              hipStream_t stream) {
  (void)in_sizes; (void)n_in; (void)ws_size;
  const float* x   = (const float*)d_in[0];
  const float* wg  = (const float*)d_in[1];
  const float* wgp = (const float*)d_in[2];
  const float* wup = (const float*)d_in[3];
  const float* wdp = (const float*)d_in[4];
  const float* wsg = (const float*)d_in[5];
  const float* wsu = (const float*)d_in[6];
  const float* wsd = (const float*)d_in[7];
  float* out = (float*)d_out;
  char* ws = (char*)d_ws;
  // ws layout (bytes): wB 27*MSZ*2 = 56623104 | xb 4194304 | actb 37748736
  //                    | tok_id 73728 | tok_w 73728 | counts 64   (~94.1 MiB)
  unsigned short* wB   = (unsigned short*)ws;
  unsigned short* xb   = (unsigned short*)(ws + 56623104);
  unsigned short* actb = (unsigned short*)(ws + 56623104 + 4194304);
  int*   tok_id = (int*)(ws + 56623104 + 4194304 + 37748736);
  float* tok_w  = (float*)(ws + 56623104 + 4194304 + 37748736 + 73728);
  int*   counts = (int*)(ws + 56623104 + 4194304 + 37748736 + 147456);

  hipMemsetAsync(counts, 0, 64, stream);
  hipMemsetAsync(out, 0, (size_t)out_size * 4, stream);
  k_prep<<<4992, 256, 0, stream>>>(x, wg, wgp, wsg, wup, wsu, wdp, wsd,
                                   wB, xb, counts, tok_id, tok_w);
  k_gemm1<<<2304, 256, 0, stream>>>(xb, wB, counts, tok_id, actb);
  k_gemm2<<<1152, 256, 0, stream>>>(actb, wB, counts, tok_id, tok_w, out);
}